// Round 6
// baseline (961.912 us; speedup 1.0000x reference)
//
#include <hip/hip_runtime.h>
#include <hip/hip_bf16.h>

// Problem constants
#define NN    8192
#define FEAT  64
#define HIDD  128
#define EMBD  128

typedef __bf16 bf16x8 __attribute__((ext_vector_type(8)));
typedef float  f32x4  __attribute__((ext_vector_type(4)));

__device__ __forceinline__ void gload16(const void* g, void* l) {
    __builtin_amdgcn_global_load_lds(
        (const __attribute__((address_space(1))) void*)g,
        (__attribute__((address_space(3))) void*)l, 16, 0, 0);
}

// ---------------------------------------------------------------------------
// proj_pack: V_r = X @ W_r^T, stored as bf16 in MFMA B-fragment layout:
//   Vp[r][kb][n][lane][j]: element = V_r[kb*32 + (lane>>4)*8 + j][n*16 + (lane&15)]
// ---------------------------------------------------------------------------
template<int KIN>
__global__ __launch_bounds__(256) void proj_pack(
    const float* __restrict__ X, const float* __restrict__ W0,
    const float* __restrict__ W1, const float* __restrict__ W2,
    __bf16* __restrict__ Vp)
{
    size_t e = (size_t)blockIdx.x * 256 + threadIdx.x;   // < 3 * 2^20
    int j  = (int)(e & 7);
    int l  = (int)((e >> 3) & 63);
    int n  = (int)((e >> 9) & 7);
    int kb = (int)((e >> 12) & 255);
    int r  = (int)(e >> 20);
    int krow = kb * 32 + (l >> 4) * 8 + j;
    int col  = n * 16 + (l & 15);
    const float* w = (r == 0 ? W0 : (r == 1 ? W1 : W2)) + (size_t)col * KIN;
    const float* x = X + (size_t)krow * KIN;
    float s = 0.f;
#pragma unroll
    for (int t = 0; t < KIN; t += 4) {
        f32x4 xv = *(const f32x4*)(x + t);
        f32x4 wv = *(const f32x4*)(w + t);
        s += xv[0]*wv[0] + xv[1]*wv[1] + xv[2]*wv[2] + xv[3]*wv[3];
    }
    Vp[e] = (__bf16)s;
}

// ---------------------------------------------------------------------------
// repack: A_r (f32, linear coalesced reads) -> bf16 fragment-packed images.
// Ap[r] layout: [(mt*8+ch)*32 + kk] images of 4096 B; image byte
//   m*1024 + l4*256 + l15*16 + h*8  holds A[mt*64+m*16+l15][ch*1024+kk*32+l4*8+h*4]
// Grid (ch 8, mt 128, r), 256 thr. Per block: 64 rows x 4KB linear row-runs.
// THIS KERNEL IS THE BANDWIDTH PROBE: pure linear streaming (m13 pattern).
// ---------------------------------------------------------------------------
__global__ __launch_bounds__(256) void repack(
    const float* __restrict__ A0, const float* __restrict__ A1,
    const float* __restrict__ A2,
    __bf16* __restrict__ Ap0, __bf16* __restrict__ Ap1, __bf16* __restrict__ Ap2)
{
    const int ch = blockIdx.x, mt = blockIdx.y, r = blockIdx.z;
    const float* A  = (r == 0) ? A0 : (r == 1) ? A1 : A2;
    __bf16*      Ap = (r == 0) ? Ap0 : (r == 1) ? Ap1 : Ap2;
    const int t    = threadIdx.x;
    const int half = t >> 7;          // row parity within round
    const int tk   = t & 127;         // 128 threads cover 1024 floats (8 each)
    const int kk   = tk >> 2;         // 0..31
    const int l4   = tk & 3;
    char* imgbase = (char*)Ap + (size_t)((mt * 8 + ch) * 32) * 4096;
    const float* asrc = A + (size_t)(mt * 64) * NN + ch * 1024 + tk * 8;

    for (int rr = 0; rr < 32; ++rr) {
        const int rowp = rr * 2 + half;               // 0..63
        f32x4 lo = *(const f32x4*)(asrc + (size_t)rowp * NN);
        f32x4 hi = *(const f32x4*)(asrc + (size_t)rowp * NN + 4);
        bf16x8 b;
        b[0] = (__bf16)lo[0]; b[1] = (__bf16)lo[1];
        b[2] = (__bf16)lo[2]; b[3] = (__bf16)lo[3];
        b[4] = (__bf16)hi[0]; b[5] = (__bf16)hi[1];
        b[6] = (__bf16)hi[2]; b[7] = (__bf16)hi[3];
        const int m = rowp >> 4, l15 = rowp & 15;
        *(bf16x8*)(imgbase + kk * 4096 + m * 1024 + l4 * 256 + l15 * 16) = b;
    }
}

// ---------------------------------------------------------------------------
// gemm_AV v6: linear-staged, raw-barrier counted-vmcnt pipeline (T4).
// Block 256 thr (4 waves); tile BM=64 x BN=128; BK=32; 96 steps (3 r x 32 kk).
// Per step per wave: packed A 1 gload16 + B 2 gload16 (3 insts; f32-A2
// fallback: 4). 2 LDS bufs x 16KB; depth-2 pipeline: vmcnt(3) waits stage(t)
// while stage(t+1) flies. Raw s_barrier (no vmcnt(0) drain). All LDS access
// lane-contiguous (conflict-free). Grid (128 mt, 8 ch) = 1024 blocks = 4/CU.
// NPACK = how many A_r are bf16-packed (3 = all, 2 = A2 read as f32).
// ---------------------------------------------------------------------------
template<int NPACK>
__global__ __launch_bounds__(256, 4) void gemm_AV(
    const float* __restrict__ A2f,
    const __bf16* __restrict__ Ap0, const __bf16* __restrict__ Ap1,
    const __bf16* __restrict__ Ap2,
    const __bf16* __restrict__ Vp, float* __restrict__ P)
{
    __shared__ __align__(16) unsigned char sbuf[2][16384];  // [A 8KB][B 8KB]

    const int mt = blockIdx.x, ch = blockIdx.y;
    const int tid = threadIdx.x;
    const int w = tid >> 6, l = tid & 63;
    const int l15 = l & 15, l4 = l >> 4;
    const int wr = w >> 1, wc = w & 1;    // wave quadrant: rows wr*32, cols wc*64

    f32x4 acc[2][4];
#pragma unroll
    for (int m = 0; m < 2; m++)
#pragma unroll
        for (int n = 0; n < 4; n++) acc[m][n] = (f32x4){0.f, 0.f, 0.f, 0.f};

    auto stage = [&](int t) {
        const int r = t >> 5, kk = t & 31;
        unsigned char* dst = sbuf[t & 1];
        if (r < NPACK) {
            const __bf16* Ap = (r == 0) ? Ap0 : (r == 1) ? Ap1 : Ap2;
            const char* src = (const char*)Ap + (size_t)((mt * 8 + ch) * 32 + kk) * 4096;
            gload16(src + w * 1024 + l * 16, dst + w * 1024 + l * 16);
        } else {
            const float* asrc = A2f + (size_t)(mt * 64 + w * 16 + l15) * NN
                                + ch * 1024 + kk * 32 + l4 * 8;
            gload16(asrc,     dst + (w * 2 + 0) * 1024 + l * 16);
            gload16(asrc + 4, dst + (w * 2 + 1) * 1024 + l * 16);
        }
        const char* bsrc = (const char*)(Vp + ((size_t)r << 20))
                           + (size_t)(ch * 32 + kk) * 8192;
        gload16(bsrc + (w * 2 + 0) * 1024 + l * 16, dst + 8192 + (w * 2 + 0) * 1024 + l * 16);
        gload16(bsrc + (w * 2 + 1) * 1024 + l * 16, dst + 8192 + (w * 2 + 1) * 1024 + l * 16);
    };

    stage(0);
    stage(1);

    for (int t = 0; t < 96; ++t) {
        // wait for stage(t) only; stage(t+1) stays in flight across the barrier
        if (t == 95)                      asm volatile("s_waitcnt vmcnt(0)" ::: "memory");
        else if (NPACK == 2 && t >= 63)   asm volatile("s_waitcnt vmcnt(4)" ::: "memory");
        else                              asm volatile("s_waitcnt vmcnt(3)" ::: "memory");
        __builtin_amdgcn_s_barrier();

        const unsigned char* buf = sbuf[t & 1];
        const bool pk = (NPACK == 3) || (t < 64);
        bf16x8 af[2];
        if (pk) {
#pragma unroll
            for (int m = 0; m < 2; ++m)
                af[m] = *(const bf16x8*)(buf + (wr * 2 + m) * 1024 + l * 16);
        } else {
#pragma unroll
            for (int m = 0; m < 2; ++m) {
                f32x4 lo = *(const f32x4*)(buf + ((wr * 2 + m) * 2 + 0) * 1024 + l * 16);
                f32x4 hi = *(const f32x4*)(buf + ((wr * 2 + m) * 2 + 1) * 1024 + l * 16);
                bf16x8 a;
                a[0] = (__bf16)lo[0]; a[1] = (__bf16)lo[1];
                a[2] = (__bf16)lo[2]; a[3] = (__bf16)lo[3];
                a[4] = (__bf16)hi[0]; a[5] = (__bf16)hi[1];
                a[6] = (__bf16)hi[2]; a[7] = (__bf16)hi[3];
                af[m] = a;
            }
        }
        bf16x8 bfr[4];
#pragma unroll
        for (int n = 0; n < 4; ++n)
            bfr[n] = *(const bf16x8*)(buf + 8192 + (wc * 4 + n) * 1024 + l * 16);
#pragma unroll
        for (int m = 0; m < 2; ++m)
#pragma unroll
            for (int n = 0; n < 4; ++n)
                acc[m][n] = __builtin_amdgcn_mfma_f32_16x16x32_bf16(af[m], bfr[n], acc[m][n], 0, 0, 0);

        // all my ds_reads landed in VGPRs before others may overwrite buf
        asm volatile("s_waitcnt lgkmcnt(0)" ::: "memory");
        __builtin_amdgcn_s_barrier();
        if (t < 94) stage(t + 2);
    }

    // C/D layout: col = lane&15, row = (lane>>4)*4 + i
    float* Pp = P + (size_t)ch * NN * 128;
#pragma unroll
    for (int m = 0; m < 2; m++)
#pragma unroll
        for (int n = 0; n < 4; n++) {
            int col = wc * 64 + n * 16 + l15;
#pragma unroll
            for (int i = 0; i < 4; i++) {
                int row = mt * 64 + wr * 32 + m * 16 + l4 * 4 + i;
                Pp[(size_t)row * 128 + col] = acc[m][n][i];
            }
        }
}

// ---------------------------------------------------------------------------
// reduce kernels: sum 8 partial slabs + bias (+relu), f32x4 vectorized
// ---------------------------------------------------------------------------
__global__ __launch_bounds__(256) void reduce_relu(
    const float* __restrict__ P, const float* __restrict__ bias,
    float* __restrict__ Hout)
{
    size_t g = (size_t)blockIdx.x * 256 + threadIdx.x;   // < 2^18
    size_t idx4 = g * 4;
    f32x4 s = *(const f32x4*)(bias + (idx4 & 127));
#pragma unroll
    for (int p = 0; p < 8; p++) s += *(const f32x4*)(P + (size_t)p * (NN * 128) + idx4);
#pragma unroll
    for (int c = 0; c < 4; c++) s[c] = s[c] > 0.f ? s[c] : 0.f;
    *(f32x4*)(Hout + idx4) = s;
}

__global__ __launch_bounds__(256) void reduce_z(
    const float* __restrict__ P, const float* __restrict__ bias,
    float* __restrict__ Zout, __bf16* __restrict__ Zb)
{
    size_t g = (size_t)blockIdx.x * 256 + threadIdx.x;
    size_t idx4 = g * 4;
    f32x4 s = *(const f32x4*)(bias + (idx4 & 127));
#pragma unroll
    for (int p = 0; p < 8; p++) s += *(const f32x4*)(P + (size_t)p * (NN * 128) + idx4);
    *(f32x4*)(Zout + idx4) = s;
#pragma unroll
    for (int c = 0; c < 4; c++) Zb[idx4 + c] = (__bf16)s[c];
}

// ---------------------------------------------------------------------------
// zzt: A_hat = Z @ Z^T, K=128, from row-major bf16 Z (2 MB, cache-resident)
// ---------------------------------------------------------------------------
__global__ __launch_bounds__(256) void zzt(
    const __bf16* __restrict__ Zb, float* __restrict__ Out)
{
    const int bx = blockIdx.x;   // col tile
    const int by = blockIdx.y;   // row tile
    const int tid = threadIdx.x;
    const int w = tid >> 6, l = tid & 63;
    const int l15 = l & 15, l4 = l >> 4;
    const int rowbase = by * 128 + w * 32;
    const int colbase = bx * 128;

    f32x4 acc[2][8];
#pragma unroll
    for (int m = 0; m < 2; m++)
#pragma unroll
        for (int n = 0; n < 8; n++) acc[m][n] = (f32x4){0.f, 0.f, 0.f, 0.f};

#pragma unroll
    for (int ks = 0; ks < 128; ks += 32) {
        bf16x8 af[2];
#pragma unroll
        for (int m = 0; m < 2; m++)
            af[m] = *(const bf16x8*)(Zb + (size_t)(rowbase + m * 16 + l15) * 128 + ks + l4 * 8);
#pragma unroll
        for (int n = 0; n < 8; n++) {
            bf16x8 bfr = *(const bf16x8*)(Zb + (size_t)(colbase + n * 16 + l15) * 128 + ks + l4 * 8);
            acc[0][n] = __builtin_amdgcn_mfma_f32_16x16x32_bf16(af[0], bfr, acc[0][n], 0, 0, 0);
            acc[1][n] = __builtin_amdgcn_mfma_f32_16x16x32_bf16(af[1], bfr, acc[1][n], 0, 0, 0);
        }
    }

#pragma unroll
    for (int m = 0; m < 2; m++)
#pragma unroll
        for (int n = 0; n < 8; n++) {
            int col = colbase + n * 16 + l15;
#pragma unroll
            for (int i = 0; i < 4; i++) {
                int row = rowbase + m * 16 + l4 * 4 + i;
                Out[(size_t)row * NN + col] = acc[m][n][i];
            }
        }
}

// ---------------------------------------------------------------------------
extern "C" void kernel_launch(void* const* d_in, const int* in_sizes, int n_in,
                              void* d_out, int out_size, void* d_ws, size_t ws_size,
                              hipStream_t stream)
{
    // setup_inputs() order: H, A_buys, A_views, A_rates,
    //   W1_0, W2_0, W1_1, W2_1, W1_2, W2_2, b1, b2
    const float* H    = (const float*)d_in[0];
    const float* A0   = (const float*)d_in[1];
    const float* A1   = (const float*)d_in[2];
    const float* A2   = (const float*)d_in[3];
    const float* W1_0 = (const float*)d_in[4];
    const float* W2_0 = (const float*)d_in[5];
    const float* W1_1 = (const float*)d_in[6];
    const float* W2_1 = (const float*)d_in[7];
    const float* W1_2 = (const float*)d_in[8];
    const float* W2_2 = (const float*)d_in[9];
    const float* b1   = (const float*)d_in[10];
    const float* b2   = (const float*)d_in[11];

    float* Zout = (float*)d_out;                     // [8192][128]
    float* Ahat = (float*)d_out + (size_t)NN * EMBD; // [8192][8192], 256MB

    char* ws = (char*)d_ws;
    float*  P  = (float*)ws;                         // 32 MB partials (8 slabs)
    __bf16* Vp = (__bf16*)(ws + ((size_t)32 << 20)); //  6 MB packed V (3 x 2MB)
    float*  H1 = (float*)(ws + ((size_t)38 << 20));  //  4 MB
    __bf16* Zb = (__bf16*)(ws + ((size_t)42 << 20)); //  2 MB

    // Packed A: Ap0/Ap1 live in the Ahat output region (exactly 2 x 128 MB;
    // zzt overwrites it at the very end). Ap2 needs ws >= 176 MB.
    __bf16* Ap0 = (__bf16*)Ahat;
    __bf16* Ap1 = (__bf16*)((char*)Ahat + ((size_t)1 << 27));
    const bool full = ws_size >= ((size_t)180 << 20);
    __bf16* Ap2 = (__bf16*)(ws + ((size_t)48 << 20));  // only used when full

    // Repack A (bandwidth probe: pure linear streaming)
    repack<<<dim3(8, 128, full ? 3 : 2), 256, 0, stream>>>(A0, A1, A2, Ap0, Ap1, Ap2);

    // Layer 1
    proj_pack<FEAT><<<12288, 256, 0, stream>>>(H, W1_0, W1_1, W1_2, Vp);
    if (full) gemm_AV<3><<<dim3(128, 8), 256, 0, stream>>>(A2, Ap0, Ap1, Ap2, Vp, P);
    else      gemm_AV<2><<<dim3(128, 8), 256, 0, stream>>>(A2, Ap0, Ap1, Ap2, Vp, P);
    reduce_relu<<<1024, 256, 0, stream>>>(P, b1, H1);

    // Layer 2
    proj_pack<HIDD><<<12288, 256, 0, stream>>>(H1, W2_0, W2_1, W2_2, Vp);
    if (full) gemm_AV<3><<<dim3(128, 8), 256, 0, stream>>>(A2, Ap0, Ap1, Ap2, Vp, P);
    else      gemm_AV<2><<<dim3(128, 8), 256, 0, stream>>>(A2, Ap0, Ap1, Ap2, Vp, P);
    reduce_z<<<1024, 256, 0, stream>>>(P, b2, Zout, Zb);

    // Decoder (overwrites Ap0/Ap1 scratch — last)
    zzt<<<dim3(64, 64), 256, 0, stream>>>(Zb, Ahat);
}

// Round 7
// 927.800 us; speedup vs baseline: 1.0368x; 1.0368x over previous
//
#include <hip/hip_runtime.h>
#include <hip/hip_bf16.h>

// Problem constants
#define NN    8192
#define FEAT  64
#define HIDD  128
#define EMBD  128

typedef __bf16 bf16x8 __attribute__((ext_vector_type(8)));
typedef float  f32x4  __attribute__((ext_vector_type(4)));

__device__ __forceinline__ void gload16(const void* g, void* l) {
    __builtin_amdgcn_global_load_lds(
        (const __attribute__((address_space(1))) void*)g,
        (__attribute__((address_space(3))) void*)l, 16, 0, 0);
}

// ---------------------------------------------------------------------------
// read_probe: DECISIVE MEASUREMENT. Pure HBM read stream (no writes except
// 8KB of block sums). 2048 blocks x 256 thr = 32 waves/CU, f32x4 x4 per
// thread per sweep, grid-strided over A0 (256 MB). Its hbm_gbps row is the
// achievable pure-read ceiling for this chip/pattern.
// ---------------------------------------------------------------------------
__global__ __launch_bounds__(256) void read_probe(
    const float* __restrict__ A, float* __restrict__ out)
{
    const size_t stride = (size_t)gridDim.x * 256 * 16;
    size_t i = ((size_t)blockIdx.x * 256 + threadIdx.x) * 16;
    f32x4 s = {0.f, 0.f, 0.f, 0.f};
    for (size_t p = i; p < (size_t)NN * NN; p += stride) {
        s += *(const f32x4*)(A + p);
        s += *(const f32x4*)(A + p + 4);
        s += *(const f32x4*)(A + p + 8);
        s += *(const f32x4*)(A + p + 12);
    }
    float v = s[0] + s[1] + s[2] + s[3];
#pragma unroll
    for (int o = 32; o; o >>= 1) v += __shfl_down(v, o, 64);
    if ((threadIdx.x & 63) == 0)
        out[blockIdx.x * 4 + (threadIdx.x >> 6)] = v;
}

// ---------------------------------------------------------------------------
// proj_pack: V_r = X @ W_r^T, stored as bf16 in MFMA B-fragment layout:
//   Vp[r][kb][n][lane][j]: element = V_r[kb*32 + (lane>>4)*8 + j][n*16 + (lane&15)]
// ---------------------------------------------------------------------------
template<int KIN>
__global__ __launch_bounds__(256) void proj_pack(
    const float* __restrict__ X, const float* __restrict__ W0,
    const float* __restrict__ W1, const float* __restrict__ W2,
    __bf16* __restrict__ Vp)
{
    size_t e = (size_t)blockIdx.x * 256 + threadIdx.x;   // < 3 * 2^20
    int j  = (int)(e & 7);
    int l  = (int)((e >> 3) & 63);
    int n  = (int)((e >> 9) & 7);
    int kb = (int)((e >> 12) & 255);
    int r  = (int)(e >> 20);
    int krow = kb * 32 + (l >> 4) * 8 + j;
    int col  = n * 16 + (l & 15);
    const float* w = (r == 0 ? W0 : (r == 1 ? W1 : W2)) + (size_t)col * KIN;
    const float* x = X + (size_t)krow * KIN;
    float s = 0.f;
#pragma unroll
    for (int t = 0; t < KIN; t += 4) {
        f32x4 xv = *(const f32x4*)(x + t);
        f32x4 wv = *(const f32x4*)(w + t);
        s += xv[0]*wv[0] + xv[1]*wv[1] + xv[2]*wv[2] + xv[3]*wv[3];
    }
    Vp[e] = (__bf16)s;
}

// ---------------------------------------------------------------------------
// gemm_AV v7: BM=128 x BN=128, BK=32, f32 A read directly (no repack).
// 4 waves; wave w owns rows w*32..w*32+31 (2 m-frags x 8 n-frags, 16 MFMA/step).
// Per step per wave: 6 gload16 (4 A f32 XOR-swizzled-source, 2 B packed).
// 3 LDS bufs x 24KB = 72KB; issue depth 3, consume wait vmcnt(12) (2 stages
// in flight); raw s_barrier + lgkmcnt guard; no vmcnt(0) in main loop (T4).
// A LDS layout: wave region w*4096, row ri at ri*128, 16B slot s holds global
// k-block (s ^ (ri&7))  -> ds_read slot = (2*l4+h) ^ (l15&7): conflict-spread.
// Grid (64 mt, 8 ch) = 512 blocks = 2/CU.
// ---------------------------------------------------------------------------
__global__ __launch_bounds__(256, 2) void gemm_AV(
    const float* __restrict__ A0, const float* __restrict__ A1,
    const float* __restrict__ A2,
    const __bf16* __restrict__ Vp, float* __restrict__ P)
{
    __shared__ __align__(16) unsigned char sbuf[3][24576];  // [A 16KB][B 8KB]

    const int mt = blockIdx.x, ch = blockIdx.y;
    const int tid = threadIdx.x;
    const int w = tid >> 6, l = tid & 63;
    const int l15 = l & 15, l4 = l >> 4;
    const int rowblk = mt * 128;

    f32x4 acc[2][8];
#pragma unroll
    for (int m = 0; m < 2; m++)
#pragma unroll
        for (int n = 0; n < 8; n++) acc[m][n] = (f32x4){0.f, 0.f, 0.f, 0.f};

    // staging lane constants
    const int srow = l >> 3;                 // row-within-8-group, == (row&7)
    const int sblk = (l & 7) ^ srow;         // inverse-swizzled source 16B block

    auto stage = [&](int t) {
        const int r = t >> 5, kk = t & 31;
        const float* Ar = (r == 0) ? A0 : (r == 1) ? A1 : A2;
        const int kglob = ch * 1024 + kk * 32;
        unsigned char* dst = sbuf[t % 3];
        // A: wave w stages its own 32 rows; inst j covers rows j*8..j*8+7.
        // LDS linear: w*4096 + j*1024 + l*16  (== row*128 + slot*16).
        const float* abase = Ar + (size_t)(rowblk + w * 32 + srow) * NN + kglob + sblk * 4;
#pragma unroll
        for (int j = 0; j < 4; ++j)
            gload16(abase + (size_t)j * 8 * NN, dst + w * 4096 + j * 1024 + l * 16);
        // B: wave w stages frags 2w, 2w+1 (Vp already fragment-packed, linear)
        const char* bsrc = (const char*)(Vp + ((size_t)r << 20)) + (size_t)(ch * 32 + kk) * 8192;
#pragma unroll
        for (int q = 0; q < 2; ++q)
            gload16(bsrc + (w * 2 + q) * 1024 + l * 16,
                    dst + 16384 + (w * 2 + q) * 1024 + l * 16);
    };

    stage(0); stage(1); stage(2);

    for (int t = 0; t < 96; ++t) {
        // wait for stage(t) only; stages t+1,t+2 (12 insts/wave) stay in flight
        if (t < 94)       asm volatile("s_waitcnt vmcnt(12)" ::: "memory");
        else if (t == 94) asm volatile("s_waitcnt vmcnt(6)"  ::: "memory");
        else              asm volatile("s_waitcnt vmcnt(0)"  ::: "memory");
        __builtin_amdgcn_s_barrier();

        const unsigned char* buf = sbuf[t % 3];
        // A fragments: rows w*32 + m*16 + l15, k-blocks 2*l4, 2*l4+1 (swizzled)
        bf16x8 af[2];
#pragma unroll
        for (int m = 0; m < 2; ++m) {
            const int ri = m * 16 + l15;
            const int b0 = (2 * l4)     ^ (l15 & 7);
            const int b1 = (2 * l4 + 1) ^ (l15 & 7);
            f32x4 lo = *(const f32x4*)(buf + w * 4096 + ri * 128 + b0 * 16);
            f32x4 hi = *(const f32x4*)(buf + w * 4096 + ri * 128 + b1 * 16);
            bf16x8 a;
            a[0] = (__bf16)lo[0]; a[1] = (__bf16)lo[1];
            a[2] = (__bf16)lo[2]; a[3] = (__bf16)lo[3];
            a[4] = (__bf16)hi[0]; a[5] = (__bf16)hi[1];
            a[6] = (__bf16)hi[2]; a[7] = (__bf16)hi[3];
            af[m] = a;
        }
        bf16x8 bfr[8];
#pragma unroll
        for (int n = 0; n < 8; ++n)
            bfr[n] = *(const bf16x8*)(buf + 16384 + n * 1024 + l * 16);
#pragma unroll
        for (int m = 0; m < 2; ++m)
#pragma unroll
            for (int n = 0; n < 8; ++n)
                acc[m][n] = __builtin_amdgcn_mfma_f32_16x16x32_bf16(af[m], bfr[n], acc[m][n], 0, 0, 0);

        // my ds_reads landed before anyone overwrites buf t%3
        asm volatile("s_waitcnt lgkmcnt(0)" ::: "memory");
        __builtin_amdgcn_s_barrier();
        if (t < 93) stage(t + 3);
    }

    // C/D layout: col = lane&15, row = (lane>>4)*4 + i
    float* Pp = P + (size_t)ch * NN * 128;
#pragma unroll
    for (int m = 0; m < 2; m++)
#pragma unroll
        for (int n = 0; n < 8; n++) {
            int col = n * 16 + l15;
#pragma unroll
            for (int i = 0; i < 4; i++) {
                int row = rowblk + w * 32 + m * 16 + l4 * 4 + i;
                Pp[(size_t)row * 128 + col] = acc[m][n][i];
            }
        }
}

// ---------------------------------------------------------------------------
// reduce kernels: sum 8 partial slabs + bias (+relu), f32x4 vectorized
// ---------------------------------------------------------------------------
__global__ __launch_bounds__(256) void reduce_relu(
    const float* __restrict__ P, const float* __restrict__ bias,
    float* __restrict__ Hout)
{
    size_t g = (size_t)blockIdx.x * 256 + threadIdx.x;   // < 2^18
    size_t idx4 = g * 4;
    f32x4 s = *(const f32x4*)(bias + (idx4 & 127));
#pragma unroll
    for (int p = 0; p < 8; p++) s += *(const f32x4*)(P + (size_t)p * (NN * 128) + idx4);
#pragma unroll
    for (int c = 0; c < 4; c++) s[c] = s[c] > 0.f ? s[c] : 0.f;
    *(f32x4*)(Hout + idx4) = s;
}

__global__ __launch_bounds__(256) void reduce_z(
    const float* __restrict__ P, const float* __restrict__ bias,
    float* __restrict__ Zout, __bf16* __restrict__ Zb)
{
    size_t g = (size_t)blockIdx.x * 256 + threadIdx.x;
    size_t idx4 = g * 4;
    f32x4 s = *(const f32x4*)(bias + (idx4 & 127));
#pragma unroll
    for (int p = 0; p < 8; p++) s += *(const f32x4*)(P + (size_t)p * (NN * 128) + idx4);
    *(f32x4*)(Zout + idx4) = s;
#pragma unroll
    for (int c = 0; c < 4; c++) Zb[idx4 + c] = (__bf16)s[c];
}

// ---------------------------------------------------------------------------
// zzt: A_hat = Z @ Z^T, K=128, from row-major bf16 Z (2 MB, cache-resident)
// ---------------------------------------------------------------------------
__global__ __launch_bounds__(256) void zzt(
    const __bf16* __restrict__ Zb, float* __restrict__ Out)
{
    const int bx = blockIdx.x;   // col tile
    const int by = blockIdx.y;   // row tile
    const int tid = threadIdx.x;
    const int w = tid >> 6, l = tid & 63;
    const int l15 = l & 15, l4 = l >> 4;
    const int rowbase = by * 128 + w * 32;
    const int colbase = bx * 128;

    f32x4 acc[2][8];
#pragma unroll
    for (int m = 0; m < 2; m++)
#pragma unroll
        for (int n = 0; n < 8; n++) acc[m][n] = (f32x4){0.f, 0.f, 0.f, 0.f};

#pragma unroll
    for (int ks = 0; ks < 128; ks += 32) {
        bf16x8 af[2];
#pragma unroll
        for (int m = 0; m < 2; m++)
            af[m] = *(const bf16x8*)(Zb + (size_t)(rowbase + m * 16 + l15) * 128 + ks + l4 * 8);
#pragma unroll
        for (int n = 0; n < 8; n++) {
            bf16x8 bfr = *(const bf16x8*)(Zb + (size_t)(colbase + n * 16 + l15) * 128 + ks + l4 * 8);
            acc[0][n] = __builtin_amdgcn_mfma_f32_16x16x32_bf16(af[0], bfr, acc[0][n], 0, 0, 0);
            acc[1][n] = __builtin_amdgcn_mfma_f32_16x16x32_bf16(af[1], bfr, acc[1][n], 0, 0, 0);
        }
    }

#pragma unroll
    for (int m = 0; m < 2; m++)
#pragma unroll
        for (int n = 0; n < 8; n++) {
            int col = colbase + n * 16 + l15;
#pragma unroll
            for (int i = 0; i < 4; i++) {
                int row = rowbase + m * 16 + l4 * 4 + i;
                Out[(size_t)row * NN + col] = acc[m][n][i];
            }
        }
}

// ---------------------------------------------------------------------------
extern "C" void kernel_launch(void* const* d_in, const int* in_sizes, int n_in,
                              void* d_out, int out_size, void* d_ws, size_t ws_size,
                              hipStream_t stream)
{
    // setup_inputs() order: H, A_buys, A_views, A_rates,
    //   W1_0, W2_0, W1_1, W2_1, W1_2, W2_2, b1, b2
    const float* H    = (const float*)d_in[0];
    const float* A0   = (const float*)d_in[1];
    const float* A1   = (const float*)d_in[2];
    const float* A2   = (const float*)d_in[3];
    const float* W1_0 = (const float*)d_in[4];
    const float* W2_0 = (const float*)d_in[5];
    const float* W1_1 = (const float*)d_in[6];
    const float* W2_1 = (const float*)d_in[7];
    const float* W1_2 = (const float*)d_in[8];
    const float* W2_2 = (const float*)d_in[9];
    const float* b1   = (const float*)d_in[10];
    const float* b2   = (const float*)d_in[11];

    float* Zout = (float*)d_out;                     // [8192][128]
    float* Ahat = (float*)d_out + (size_t)NN * EMBD; // [8192][8192]

    char* ws = (char*)d_ws;
    float*  P   = (float*)ws;                         // 32 MB partials (8 slabs)
    __bf16* Vp  = (__bf16*)(ws + ((size_t)32 << 20)); //  6 MB packed V (3 x 2MB)
    float*  H1  = (float*)(ws + ((size_t)38 << 20));  //  4 MB
    __bf16* Zb  = (__bf16*)(ws + ((size_t)42 << 20)); //  2 MB
    float*  pb  = (float*)(ws + ((size_t)44 << 20));  //  8 KB probe sums

    // Decisive measurement: pure-read HBM ceiling (256 MB, no writes)
    read_probe<<<2048, 256, 0, stream>>>(A0, pb);

    // Layer 1
    proj_pack<FEAT><<<12288, 256, 0, stream>>>(H, W1_0, W1_1, W1_2, Vp);
    gemm_AV<<<dim3(64, 8), 256, 0, stream>>>(A0, A1, A2, Vp, P);
    reduce_relu<<<1024, 256, 0, stream>>>(P, b1, H1);

    // Layer 2
    proj_pack<HIDD><<<12288, 256, 0, stream>>>(H1, W2_0, W2_1, W2_2, Vp);
    gemm_AV<<<dim3(64, 8), 256, 0, stream>>>(A0, A1, A2, Vp, P);
    reduce_z<<<1024, 256, 0, stream>>>(P, b2, Zout, Zb);

    // Decoder
    zzt<<<dim3(64, 64), 256, 0, stream>>>(Zb, Ahat);
}

// Round 8
// 775.246 us; speedup vs baseline: 1.2408x; 1.1968x over previous
//
#include <hip/hip_runtime.h>
#include <hip/hip_bf16.h>

// Problem constants
#define NN    8192
#define FEAT  64
#define HIDD  128
#define EMBD  128

typedef __bf16 bf16x8 __attribute__((ext_vector_type(8)));
typedef float  f32x4  __attribute__((ext_vector_type(4)));

__device__ __forceinline__ void gload16(const void* g, void* l) {
    __builtin_amdgcn_global_load_lds(
        (const __attribute__((address_space(1))) void*)g,
        (__attribute__((address_space(3))) void*)l, 16, 0, 0);
}

// ---------------------------------------------------------------------------
// read_probe v2: DECISIVE MEASUREMENT, m13-correct this time.
// Lane-contiguous f32x4 (64 lanes x 16B = 1KB per instruction), grid-strided,
// unroll-4 for 4 independent loads in flight, 2048 blocks = 32 waves/CU.
// Sweeps ALL THREE A matrices (768 MB) so it lands in the top-5 with counters.
// ---------------------------------------------------------------------------
__global__ __launch_bounds__(256) void read_probe(
    const float* __restrict__ A0, const float* __restrict__ A1,
    const float* __restrict__ A2, float* __restrict__ out)
{
    const size_t nvec = (size_t)NN * NN / 4;          // f32x4 count per matrix
    const size_t gs   = (size_t)gridDim.x * 256;
    f32x4 s = {0.f, 0.f, 0.f, 0.f};
    const float* As[3] = {A0, A1, A2};
#pragma unroll
    for (int r = 0; r < 3; ++r) {
        const f32x4* p = (const f32x4*)As[r];
        for (size_t i = (size_t)blockIdx.x * 256 + threadIdx.x; i < nvec; i += gs * 4) {
            s += p[i];
            s += p[i + gs];
            s += p[i + 2 * gs];
            s += p[i + 3 * gs];
        }
    }
    float v = s[0] + s[1] + s[2] + s[3];
#pragma unroll
    for (int o = 32; o; o >>= 1) v += __shfl_down(v, o, 64);
    if ((threadIdx.x & 63) == 0)
        out[blockIdx.x * 4 + (threadIdx.x >> 6)] = v;
}

// ---------------------------------------------------------------------------
// proj_pack v2: V_r = X @ W_r^T into MFMA B-fragment layout
//   Vp elem ((r<<20) + kb*4096 + n*512 + l*8 + j) = V_r[kb*32+(l>>4)*8+j][n*16+(l&15)]
// One block per kb (32 krows). X-slab (contiguous 32*KIN floats) staged in LDS
// once; thread (c = tid&127, h = tid>>7) caches W_r[c][:] in regs, computes 16
// krows, writes two contiguous bf16x8 per r. W re-reads are L2-hot.
// ---------------------------------------------------------------------------
template<int KIN>
__global__ __launch_bounds__(256) void proj_pack(
    const float* __restrict__ X, const float* __restrict__ W0,
    const float* __restrict__ W1, const float* __restrict__ W2,
    __bf16* __restrict__ Vp)
{
    __shared__ float sx[32 * KIN];
    const int kb  = blockIdx.x;
    const int tid = threadIdx.x;
    // stage X rows kb*32 .. kb*32+31 (fully contiguous block of 32*KIN floats)
    {
        const f32x4* src = (const f32x4*)(X + (size_t)kb * 32 * KIN);
#pragma unroll
        for (int i = 0; i < 32 * KIN / 4 / 256; ++i)
            ((f32x4*)sx)[tid + i * 256] = src[tid + i * 256];
    }
    __syncthreads();

    const int c = tid & 127, h = tid >> 7;
    const int n = c >> 4, c15 = c & 15;
    const float* Ws[3] = {W0, W1, W2};
#pragma unroll
    for (int r = 0; r < 3; ++r) {
        f32x4 wreg[KIN / 4];
        const f32x4* wrow = (const f32x4*)(Ws[r] + (size_t)c * KIN);
#pragma unroll
        for (int j = 0; j < KIN / 4; ++j) wreg[j] = wrow[j];
        float d[16];
#pragma unroll
        for (int i = 0; i < 16; ++i) {
            const f32x4* xr = (const f32x4*)(sx + (h * 16 + i) * KIN);
            float s = 0.f;
#pragma unroll
            for (int j = 0; j < KIN / 4; ++j) {
                f32x4 xv = xr[j];
                s += xv[0]*wreg[j][0] + xv[1]*wreg[j][1] + xv[2]*wreg[j][2] + xv[3]*wreg[j][3];
            }
            d[i] = s;
        }
#pragma unroll
        for (int g = 0; g < 2; ++g) {
            bf16x8 b;
#pragma unroll
            for (int j = 0; j < 8; ++j) b[j] = (__bf16)d[g * 8 + j];
            const int l = (h * 2 + g) * 16 + c15;
            *(bf16x8*)(Vp + ((size_t)r << 20) + kb * 4096 + n * 512 + l * 8) = b;
        }
    }
}

// ---------------------------------------------------------------------------
// gemm_AV v8: BM=64 x BN=128, BK=32; 4 waves, wave = 16 rows x 128 cols
// (acc[8], 32 AGPR). 2 LDS bufs x 16KB = 32KB -> 4 blocks/CU, 16 waves/CU.
// Per step per wave: 4 gload16 (2 A f32 XOR-swizzled source, 2 B packed).
// Counted vmcnt(4) (stage t+1 in flight), raw s_barrier, lgkmcnt guard,
// no vmcnt(0) in main loop. Grid (128 mt, 8 ch) = 1024 blocks.
// ---------------------------------------------------------------------------
__global__ __launch_bounds__(256, 4) void gemm_AV(
    const float* __restrict__ A0, const float* __restrict__ A1,
    const float* __restrict__ A2,
    const __bf16* __restrict__ Vp, float* __restrict__ P)
{
    __shared__ __align__(16) unsigned char sbuf[2][16384];  // [A 8KB][B 8KB]

    const int mt = blockIdx.x, ch = blockIdx.y;
    const int tid = threadIdx.x;
    const int w = tid >> 6, l = tid & 63;
    const int l15 = l & 15, l4 = l >> 4;
    const int rowblk = mt * 64;

    f32x4 acc[8];
#pragma unroll
    for (int n = 0; n < 8; n++) acc[n] = (f32x4){0.f, 0.f, 0.f, 0.f};

    const int srow = l >> 3;                 // row-within-8-group == (row&7)
    const int sblk = (l & 7) ^ srow;         // inverse-swizzled source 16B block

    auto stage = [&](int t) {
        const int r = t >> 5, kk = t & 31;
        const float* Ar = (r == 0) ? A0 : (r == 1) ? A1 : A2;
        const int kglob = ch * 1024 + kk * 32;
        unsigned char* dst = sbuf[t & 1];
        // A: wave w stages its 16 rows; inst j covers rows j*8..j*8+7
        const float* abase = Ar + (size_t)(rowblk + w * 16 + srow) * NN + kglob + sblk * 4;
#pragma unroll
        for (int j = 0; j < 2; ++j)
            gload16(abase + (size_t)j * 8 * NN, dst + w * 2048 + j * 1024 + l * 16);
        // B: wave w stages frags 2w, 2w+1 (Vp fragment-packed, linear 1KB/inst)
        const char* bsrc = (const char*)(Vp + ((size_t)r << 20)) + (size_t)(ch * 32 + kk) * 8192;
#pragma unroll
        for (int q = 0; q < 2; ++q)
            gload16(bsrc + (w * 2 + q) * 1024 + l * 16,
                    dst + 8192 + (w * 2 + q) * 1024 + l * 16);
    };

    stage(0); stage(1);

    for (int t = 0; t < 96; ++t) {
        if (t < 95) asm volatile("s_waitcnt vmcnt(4)" ::: "memory");
        else        asm volatile("s_waitcnt vmcnt(0)" ::: "memory");
        __builtin_amdgcn_s_barrier();

        const unsigned char* buf = sbuf[t & 1];
        // A fragment: wave-local row l15, k-blocks 2*l4, 2*l4+1 (XOR-swizzled)
        const int b0 = (2 * l4) ^ (l15 & 7);
        f32x4 lo = *(const f32x4*)(buf + w * 2048 + l15 * 128 + b0 * 16);
        f32x4 hi = *(const f32x4*)(buf + w * 2048 + l15 * 128 + (b0 ^ 1) * 16);
        bf16x8 af;
        af[0] = (__bf16)lo[0]; af[1] = (__bf16)lo[1];
        af[2] = (__bf16)lo[2]; af[3] = (__bf16)lo[3];
        af[4] = (__bf16)hi[0]; af[5] = (__bf16)hi[1];
        af[6] = (__bf16)hi[2]; af[7] = (__bf16)hi[3];
        bf16x8 bfr[8];
#pragma unroll
        for (int n = 0; n < 8; ++n)
            bfr[n] = *(const bf16x8*)(buf + 8192 + n * 1024 + l * 16);
#pragma unroll
        for (int n = 0; n < 8; ++n)
            acc[n] = __builtin_amdgcn_mfma_f32_16x16x32_bf16(af, bfr[n], acc[n], 0, 0, 0);

        asm volatile("s_waitcnt lgkmcnt(0)" ::: "memory");
        __builtin_amdgcn_s_barrier();
        if (t < 94) stage(t + 2);
    }

    // C/D layout: col = lane&15, row = (lane>>4)*4 + i
    float* Pp = P + (size_t)ch * NN * 128;
#pragma unroll
    for (int n = 0; n < 8; n++) {
        int col = n * 16 + l15;
#pragma unroll
        for (int i = 0; i < 4; i++) {
            int row = rowblk + w * 16 + l4 * 4 + i;
            Pp[(size_t)row * 128 + col] = acc[n][i];
        }
    }
}

// ---------------------------------------------------------------------------
// reduce kernels: sum 8 partial slabs + bias (+relu), f32x4 vectorized
// ---------------------------------------------------------------------------
__global__ __launch_bounds__(256) void reduce_relu(
    const float* __restrict__ P, const float* __restrict__ bias,
    float* __restrict__ Hout)
{
    size_t g = (size_t)blockIdx.x * 256 + threadIdx.x;   // < 2^18
    size_t idx4 = g * 4;
    f32x4 s = *(const f32x4*)(bias + (idx4 & 127));
#pragma unroll
    for (int p = 0; p < 8; p++) s += *(const f32x4*)(P + (size_t)p * (NN * 128) + idx4);
#pragma unroll
    for (int c = 0; c < 4; c++) s[c] = s[c] > 0.f ? s[c] : 0.f;
    *(f32x4*)(Hout + idx4) = s;
}

__global__ __launch_bounds__(256) void reduce_z(
    const float* __restrict__ P, const float* __restrict__ bias,
    float* __restrict__ Zout, __bf16* __restrict__ Zb)
{
    size_t g = (size_t)blockIdx.x * 256 + threadIdx.x;
    size_t idx4 = g * 4;
    f32x4 s = *(const f32x4*)(bias + (idx4 & 127));
#pragma unroll
    for (int p = 0; p < 8; p++) s += *(const f32x4*)(P + (size_t)p * (NN * 128) + idx4);
    *(f32x4*)(Zout + idx4) = s;
#pragma unroll
    for (int c = 0; c < 4; c++) Zb[idx4 + c] = (__bf16)s[c];
}

// ---------------------------------------------------------------------------
// zzt v2: A_hat = Z @ Z^T with LDS-transposed, write-coalesced epilogue.
// Compute as before (Zb 2MB, L2-resident). Epilogue: each wave dumps its
// 32x128 slab into padded LDS (stride 132 breaks bank alignment), reads back
// row-major f32x4 and stores 2 rows per inst = 2 x 512B contiguous segments.
// ---------------------------------------------------------------------------
__global__ __launch_bounds__(256) void zzt(
    const __bf16* __restrict__ Zb, float* __restrict__ Out)
{
    __shared__ float tz[4][32][132];   // 67.6 KB, per-wave private slabs

    const int bx = blockIdx.x;   // col tile
    const int by = blockIdx.y;   // row tile
    const int tid = threadIdx.x;
    const int w = tid >> 6, l = tid & 63;
    const int l15 = l & 15, l4 = l >> 4;
    const int rowbase = by * 128 + w * 32;
    const int colbase = bx * 128;

    f32x4 acc[2][8];
#pragma unroll
    for (int m = 0; m < 2; m++)
#pragma unroll
        for (int n = 0; n < 8; n++) acc[m][n] = (f32x4){0.f, 0.f, 0.f, 0.f};

#pragma unroll
    for (int ks = 0; ks < 128; ks += 32) {
        bf16x8 af[2];
#pragma unroll
        for (int m = 0; m < 2; m++)
            af[m] = *(const bf16x8*)(Zb + (size_t)(rowbase + m * 16 + l15) * 128 + ks + l4 * 8);
#pragma unroll
        for (int n = 0; n < 8; n++) {
            bf16x8 bfr = *(const bf16x8*)(Zb + (size_t)(colbase + n * 16 + l15) * 128 + ks + l4 * 8);
            acc[0][n] = __builtin_amdgcn_mfma_f32_16x16x32_bf16(af[0], bfr, acc[0][n], 0, 0, 0);
            acc[1][n] = __builtin_amdgcn_mfma_f32_16x16x32_bf16(af[1], bfr, acc[1][n], 0, 0, 0);
        }
    }

    // acc -> LDS (wave-local; LDS ops from one wave execute in order)
#pragma unroll
    for (int m = 0; m < 2; m++)
#pragma unroll
        for (int n = 0; n < 8; n++)
#pragma unroll
            for (int i = 0; i < 4; i++)
                tz[w][m * 16 + l4 * 4 + i][n * 16 + l15] = acc[m][n][i];
    asm volatile("s_waitcnt lgkmcnt(0)" ::: "memory");

    // LDS -> global: inst q covers rows q*2, q*2+1 (512B contiguous each)
    const int rp = l >> 5;           // row within pair
    const int c4 = l & 31;           // f32x4 index within row
#pragma unroll
    for (int q = 0; q < 16; ++q) {
        f32x4 v = *(const f32x4*)&tz[w][q * 2 + rp][c4 * 4];
        *(f32x4*)(Out + (size_t)(rowbase + q * 2 + rp) * NN + colbase + c4 * 4) = v;
    }
}

// ---------------------------------------------------------------------------
extern "C" void kernel_launch(void* const* d_in, const int* in_sizes, int n_in,
                              void* d_out, int out_size, void* d_ws, size_t ws_size,
                              hipStream_t stream)
{
    // setup_inputs() order: H, A_buys, A_views, A_rates,
    //   W1_0, W2_0, W1_1, W2_1, W1_2, W2_2, b1, b2
    const float* H    = (const float*)d_in[0];
    const float* A0   = (const float*)d_in[1];
    const float* A1   = (const float*)d_in[2];
    const float* A2   = (const float*)d_in[3];
    const float* W1_0 = (const float*)d_in[4];
    const float* W2_0 = (const float*)d_in[5];
    const float* W1_1 = (const float*)d_in[6];
    const float* W2_1 = (const float*)d_in[7];
    const float* W1_2 = (const float*)d_in[8];
    const float* W2_2 = (const float*)d_in[9];
    const float* b1   = (const float*)d_in[10];
    const float* b2   = (const float*)d_in[11];

    float* Zout = (float*)d_out;                     // [8192][128]
    float* Ahat = (float*)d_out + (size_t)NN * EMBD; // [8192][8192]

    char* ws = (char*)d_ws;
    float*  P   = (float*)ws;                         // 32 MB partials (8 slabs)
    __bf16* Vp  = (__bf16*)(ws + ((size_t)32 << 20)); //  6 MB packed V (3 x 2MB)
    float*  H1  = (float*)(ws + ((size_t)38 << 20));  //  4 MB
    __bf16* Zb  = (__bf16*)(ws + ((size_t)42 << 20)); //  2 MB
    float*  pb  = (float*)(ws + ((size_t)44 << 20));  //  8 KB probe sums

    // Decisive measurement: pure-read HBM ceiling, m13-correct pattern (768 MB)
    read_probe<<<2048, 256, 0, stream>>>(A0, A1, A2, pb);

    // Layer 1
    proj_pack<FEAT><<<256, 256, 0, stream>>>(H, W1_0, W1_1, W1_2, Vp);
    gemm_AV<<<dim3(128, 8), 256, 0, stream>>>(A0, A1, A2, Vp, P);
    reduce_relu<<<1024, 256, 0, stream>>>(P, b1, H1);

    // Layer 2
    proj_pack<HIDD><<<256, 256, 0, stream>>>(H1, W2_0, W2_1, W2_2, Vp);
    gemm_AV<<<dim3(128, 8), 256, 0, stream>>>(A0, A1, A2, Vp, P);
    reduce_z<<<1024, 256, 0, stream>>>(P, b2, Zout, Zb);

    // Decoder
    zzt<<<dim3(64, 64), 256, 0, stream>>>(Zb, Ahat);
}

// Round 9
// 606.089 us; speedup vs baseline: 1.5871x; 1.2791x over previous
//
#include <hip/hip_runtime.h>
#include <hip/hip_bf16.h>

// Problem constants
#define NN    8192
#define FEAT  64
#define HIDD  128
#define EMBD  128

typedef __bf16 bf16x8 __attribute__((ext_vector_type(8)));
typedef float  f32x4  __attribute__((ext_vector_type(4)));

__device__ __forceinline__ void gload16(const void* g, void* l) {
    __builtin_amdgcn_global_load_lds(
        (const __attribute__((address_space(1))) void*)g,
        (__attribute__((address_space(3))) void*)l, 16, 0, 0);
}

// ---------------------------------------------------------------------------
// proj_pack: V_r = X @ W_r^T into MFMA B-fragment layout
//   Vp elem ((r<<20) + kb*4096 + n*512 + l*8 + j) = V_r[kb*32+(l>>4)*8+j][n*16+(l&15)]
// ---------------------------------------------------------------------------
template<int KIN>
__global__ __launch_bounds__(256) void proj_pack(
    const float* __restrict__ X, const float* __restrict__ W0,
    const float* __restrict__ W1, const float* __restrict__ W2,
    __bf16* __restrict__ Vp)
{
    __shared__ float sx[32 * KIN];
    const int kb  = blockIdx.x;
    const int tid = threadIdx.x;
    {
        const f32x4* src = (const f32x4*)(X + (size_t)kb * 32 * KIN);
#pragma unroll
        for (int i = 0; i < 32 * KIN / 4 / 256; ++i)
            ((f32x4*)sx)[tid + i * 256] = src[tid + i * 256];
    }
    __syncthreads();

    const int c = tid & 127, h = tid >> 7;
    const int n = c >> 4, c15 = c & 15;
    const float* Ws[3] = {W0, W1, W2};
#pragma unroll
    for (int r = 0; r < 3; ++r) {
        f32x4 wreg[KIN / 4];
        const f32x4* wrow = (const f32x4*)(Ws[r] + (size_t)c * KIN);
#pragma unroll
        for (int j = 0; j < KIN / 4; ++j) wreg[j] = wrow[j];
        float d[16];
#pragma unroll
        for (int i = 0; i < 16; ++i) {
            const f32x4* xr = (const f32x4*)(sx + (h * 16 + i) * KIN);
            float s = 0.f;
#pragma unroll
            for (int j = 0; j < KIN / 4; ++j) {
                f32x4 xv = xr[j];
                s += xv[0]*wreg[j][0] + xv[1]*wreg[j][1] + xv[2]*wreg[j][2] + xv[3]*wreg[j][3];
            }
            d[i] = s;
        }
#pragma unroll
        for (int g = 0; g < 2; ++g) {
            bf16x8 b;
#pragma unroll
            for (int j = 0; j < 8; ++j) b[j] = (__bf16)d[g * 8 + j];
            const int l = (h * 2 + g) * 16 + c15;
            *(bf16x8*)(Vp + ((size_t)r << 20) + kb * 4096 + n * 512 + l * 8) = b;
        }
    }
}

// ---------------------------------------------------------------------------
// gemm_l1: layer-1 GEMM (f32 A) + FUSED A-compression.  Structure = v8
// (BM=64, 4 waves, 2x16KB LDS, counted vmcnt, raw barriers).  Each wave
// stores its converted bf16 A-fragment (1KB, lane-contiguous) to Apk_r in
// the exact layout gemm_l2 stages from:
//   Apk_r byte ((mt*8+ch)*32+kk)*4096 + w*1024 + l*16
// vmcnt math: consume t needs stage(t) done; newer ops = store(t-1) (if
// emitted) + stage(t+1) (4 loads) -> wait 5 (or 4 when store skipped).
// PACK2: whether A2 is packed (needs ws room) -- r<2 always packed to d_out.
// ---------------------------------------------------------------------------
template<bool PACK2>
__global__ __launch_bounds__(256, 4) void gemm_l1(
    const float* __restrict__ A0, const float* __restrict__ A1,
    const float* __restrict__ A2,
    const __bf16* __restrict__ Vp, float* __restrict__ P,
    __bf16* __restrict__ Apk0, __bf16* __restrict__ Apk1,
    __bf16* __restrict__ Apk2)
{
    __shared__ __align__(16) unsigned char sbuf[2][16384];  // [A 8KB f32][B 8KB]

    const int mt = blockIdx.x, ch = blockIdx.y;
    const int tid = threadIdx.x;
    const int w = tid >> 6, l = tid & 63;
    const int l15 = l & 15, l4 = l >> 4;
    const int rowblk = mt * 64;

    f32x4 acc[8];
#pragma unroll
    for (int n = 0; n < 8; n++) acc[n] = (f32x4){0.f, 0.f, 0.f, 0.f};

    const int srow = l >> 3;                 // row-within-8-group == (row&7)
    const int sblk = (l & 7) ^ srow;         // inverse-swizzled source 16B block

    auto stage = [&](int t) {
        const int r = t >> 5, kk = t & 31;
        const float* Ar = (r == 0) ? A0 : (r == 1) ? A1 : A2;
        const int kglob = ch * 1024 + kk * 32;
        unsigned char* dst = sbuf[t & 1];
        const float* abase = Ar + (size_t)(rowblk + w * 16 + srow) * NN + kglob + sblk * 4;
#pragma unroll
        for (int j = 0; j < 2; ++j)
            gload16(abase + (size_t)j * 8 * NN, dst + w * 2048 + j * 1024 + l * 16);
        const char* bsrc = (const char*)(Vp + ((size_t)r << 20)) + (size_t)(ch * 32 + kk) * 8192;
#pragma unroll
        for (int q = 0; q < 2; ++q)
            gload16(bsrc + (w * 2 + q) * 1024 + l * 16,
                    dst + 8192 + (w * 2 + q) * 1024 + l * 16);
    };

    stage(0); stage(1);

    for (int t = 0; t < 96; ++t) {
        if (t == 0)        asm volatile("s_waitcnt vmcnt(4)" ::: "memory");
        else if (t == 95)  asm volatile("s_waitcnt vmcnt(0)" ::: "memory");
        else if (PACK2)    asm volatile("s_waitcnt vmcnt(5)" ::: "memory");
        else if (t <= 64)  asm volatile("s_waitcnt vmcnt(5)" ::: "memory");
        else               asm volatile("s_waitcnt vmcnt(4)" ::: "memory");
        __builtin_amdgcn_s_barrier();

        const unsigned char* buf = sbuf[t & 1];
        const int b0 = (2 * l4) ^ (l15 & 7);
        f32x4 lo = *(const f32x4*)(buf + w * 2048 + l15 * 128 + b0 * 16);
        f32x4 hi = *(const f32x4*)(buf + w * 2048 + l15 * 128 + (b0 ^ 1) * 16);
        bf16x8 af;
        af[0] = (__bf16)lo[0]; af[1] = (__bf16)lo[1];
        af[2] = (__bf16)lo[2]; af[3] = (__bf16)lo[3];
        af[4] = (__bf16)hi[0]; af[5] = (__bf16)hi[1];
        af[6] = (__bf16)hi[2]; af[7] = (__bf16)hi[3];
        bf16x8 bfr[8];
#pragma unroll
        for (int n = 0; n < 8; ++n)
            bfr[n] = *(const bf16x8*)(buf + 8192 + n * 1024 + l * 16);
#pragma unroll
        for (int n = 0; n < 8; ++n)
            acc[n] = __builtin_amdgcn_mfma_f32_16x16x32_bf16(af, bfr[n], acc[n], 0, 0, 0);

        // fused A-compression: store this wave's bf16 fragment (lane-contig 1KB)
        {
            const int r = t >> 5, kk = t & 31;
            if (r < 2 || PACK2) {
                __bf16* Apk = (r == 0) ? Apk0 : (r == 1) ? Apk1 : Apk2;
                *(bf16x8*)(Apk + ((size_t)(mt * 8 + ch) * 32 + kk) * 2048 + w * 512 + l * 8) = af;
            }
        }

        asm volatile("s_waitcnt lgkmcnt(0)" ::: "memory");
        __builtin_amdgcn_s_barrier();
        if (t < 94) stage(t + 2);
    }

    float* Pp = P + (size_t)ch * NN * 128;
#pragma unroll
    for (int n = 0; n < 8; n++) {
        int col = n * 16 + l15;
#pragma unroll
        for (int i = 0; i < 4; i++) {
            int row = rowblk + w * 16 + l4 * 4 + i;
            Pp[(size_t)row * 128 + col] = acc[n][i];
        }
    }
}

// ---------------------------------------------------------------------------
// gemm_l2: layer-2 GEMM consuming packed bf16 A (half the bytes).
// Per step per wave: packed r -> 1 A gload16 + 2 B; fallback r (f32 A2 when
// NPACK==2) -> 2 + 2.  NP3 LDS = 2x12KB -> up to 6 blocks/CU.
// ---------------------------------------------------------------------------
template<int NPACK>
__global__ __launch_bounds__(256, 4) void gemm_l2(
    const float* __restrict__ A2f,
    const __bf16* __restrict__ Apk0, const __bf16* __restrict__ Apk1,
    const __bf16* __restrict__ Apk2,
    const __bf16* __restrict__ Vp, float* __restrict__ P)
{
    constexpr int ABYTES = (NPACK == 3) ? 4096 : 8192;
    __shared__ __align__(16) unsigned char sbuf[2][ABYTES + 8192];

    const int mt = blockIdx.x, ch = blockIdx.y;
    const int tid = threadIdx.x;
    const int w = tid >> 6, l = tid & 63;
    const int l15 = l & 15, l4 = l >> 4;
    const int rowblk = mt * 64;

    f32x4 acc[8];
#pragma unroll
    for (int n = 0; n < 8; n++) acc[n] = (f32x4){0.f, 0.f, 0.f, 0.f};

    const int srow = l >> 3;
    const int sblk = (l & 7) ^ srow;

    auto stage = [&](int t) {
        const int r = t >> 5, kk = t & 31;
        unsigned char* dst = sbuf[t & 1];
        if (r < NPACK) {
            const __bf16* Apk = (r == 0) ? Apk0 : (r == 1) ? Apk1 : Apk2;
            const char* asrc = (const char*)Apk + ((size_t)(mt * 8 + ch) * 32 + kk) * 4096;
            gload16(asrc + w * 1024 + l * 16, dst + w * 1024 + l * 16);
        } else {
            const int kglob = ch * 1024 + kk * 32;
            const float* abase = A2f + (size_t)(rowblk + w * 16 + srow) * NN + kglob + sblk * 4;
#pragma unroll
            for (int j = 0; j < 2; ++j)
                gload16(abase + (size_t)j * 8 * NN, dst + w * 2048 + j * 1024 + l * 16);
        }
        const char* bsrc = (const char*)(Vp + ((size_t)r << 20)) + (size_t)(ch * 32 + kk) * 8192;
#pragma unroll
        for (int q = 0; q < 2; ++q)
            gload16(bsrc + (w * 2 + q) * 1024 + l * 16,
                    dst + ABYTES + (w * 2 + q) * 1024 + l * 16);
    };

    stage(0); stage(1);

    for (int t = 0; t < 96; ++t) {
        if (NPACK == 3) {
            if (t < 95) asm volatile("s_waitcnt vmcnt(3)" ::: "memory");
            else        asm volatile("s_waitcnt vmcnt(0)" ::: "memory");
        } else {
            if (t <= 62)      asm volatile("s_waitcnt vmcnt(3)" ::: "memory");
            else if (t < 95)  asm volatile("s_waitcnt vmcnt(4)" ::: "memory");
            else              asm volatile("s_waitcnt vmcnt(0)" ::: "memory");
        }
        __builtin_amdgcn_s_barrier();

        const unsigned char* buf = sbuf[t & 1];
        const int r = t >> 5;
        bf16x8 af;
        if (r < NPACK) {
            af = *(const bf16x8*)(buf + w * 1024 + l * 16);
        } else {
            const int b0 = (2 * l4) ^ (l15 & 7);
            f32x4 lo = *(const f32x4*)(buf + w * 2048 + l15 * 128 + b0 * 16);
            f32x4 hi = *(const f32x4*)(buf + w * 2048 + l15 * 128 + (b0 ^ 1) * 16);
            af[0] = (__bf16)lo[0]; af[1] = (__bf16)lo[1];
            af[2] = (__bf16)lo[2]; af[3] = (__bf16)lo[3];
            af[4] = (__bf16)hi[0]; af[5] = (__bf16)hi[1];
            af[6] = (__bf16)hi[2]; af[7] = (__bf16)hi[3];
        }
        bf16x8 bfr[8];
#pragma unroll
        for (int n = 0; n < 8; ++n)
            bfr[n] = *(const bf16x8*)(buf + ABYTES + n * 1024 + l * 16);
#pragma unroll
        for (int n = 0; n < 8; ++n)
            acc[n] = __builtin_amdgcn_mfma_f32_16x16x32_bf16(af, bfr[n], acc[n], 0, 0, 0);

        asm volatile("s_waitcnt lgkmcnt(0)" ::: "memory");
        __builtin_amdgcn_s_barrier();
        if (t < 94) stage(t + 2);
    }

    float* Pp = P + (size_t)ch * NN * 128;
#pragma unroll
    for (int n = 0; n < 8; n++) {
        int col = n * 16 + l15;
#pragma unroll
        for (int i = 0; i < 4; i++) {
            int row = rowblk + w * 16 + l4 * 4 + i;
            Pp[(size_t)row * 128 + col] = acc[n][i];
        }
    }
}

// ---------------------------------------------------------------------------
// reduce kernels: sum 8 partial slabs + bias (+relu), f32x4 vectorized
// ---------------------------------------------------------------------------
__global__ __launch_bounds__(256) void reduce_relu(
    const float* __restrict__ P, const float* __restrict__ bias,
    float* __restrict__ Hout)
{
    size_t g = (size_t)blockIdx.x * 256 + threadIdx.x;
    size_t idx4 = g * 4;
    f32x4 s = *(const f32x4*)(bias + (idx4 & 127));
#pragma unroll
    for (int p = 0; p < 8; p++) s += *(const f32x4*)(P + (size_t)p * (NN * 128) + idx4);
#pragma unroll
    for (int c = 0; c < 4; c++) s[c] = s[c] > 0.f ? s[c] : 0.f;
    *(f32x4*)(Hout + idx4) = s;
}

__global__ __launch_bounds__(256) void reduce_z(
    const float* __restrict__ P, const float* __restrict__ bias,
    float* __restrict__ Zout, __bf16* __restrict__ Zb)
{
    size_t g = (size_t)blockIdx.x * 256 + threadIdx.x;
    size_t idx4 = g * 4;
    f32x4 s = *(const f32x4*)(bias + (idx4 & 127));
#pragma unroll
    for (int p = 0; p < 8; p++) s += *(const f32x4*)(P + (size_t)p * (NN * 128) + idx4);
    *(f32x4*)(Zout + idx4) = s;
#pragma unroll
    for (int c = 0; c < 4; c++) Zb[idx4 + c] = (__bf16)s[c];
}

// ---------------------------------------------------------------------------
// zzt: A_hat = Z @ Z^T with LDS-transposed, write-coalesced epilogue.
// ---------------------------------------------------------------------------
__global__ __launch_bounds__(256) void zzt(
    const __bf16* __restrict__ Zb, float* __restrict__ Out)
{
    __shared__ float tz[4][32][132];

    const int bx = blockIdx.x;
    const int by = blockIdx.y;
    const int tid = threadIdx.x;
    const int w = tid >> 6, l = tid & 63;
    const int l15 = l & 15, l4 = l >> 4;
    const int rowbase = by * 128 + w * 32;
    const int colbase = bx * 128;

    f32x4 acc[2][8];
#pragma unroll
    for (int m = 0; m < 2; m++)
#pragma unroll
        for (int n = 0; n < 8; n++) acc[m][n] = (f32x4){0.f, 0.f, 0.f, 0.f};

#pragma unroll
    for (int ks = 0; ks < 128; ks += 32) {
        bf16x8 af[2];
#pragma unroll
        for (int m = 0; m < 2; m++)
            af[m] = *(const bf16x8*)(Zb + (size_t)(rowbase + m * 16 + l15) * 128 + ks + l4 * 8);
#pragma unroll
        for (int n = 0; n < 8; n++) {
            bf16x8 bfr = *(const bf16x8*)(Zb + (size_t)(colbase + n * 16 + l15) * 128 + ks + l4 * 8);
            acc[0][n] = __builtin_amdgcn_mfma_f32_16x16x32_bf16(af[0], bfr, acc[0][n], 0, 0, 0);
            acc[1][n] = __builtin_amdgcn_mfma_f32_16x16x32_bf16(af[1], bfr, acc[1][n], 0, 0, 0);
        }
    }

#pragma unroll
    for (int m = 0; m < 2; m++)
#pragma unroll
        for (int n = 0; n < 8; n++)
#pragma unroll
            for (int i = 0; i < 4; i++)
                tz[w][m * 16 + l4 * 4 + i][n * 16 + l15] = acc[m][n][i];
    asm volatile("s_waitcnt lgkmcnt(0)" ::: "memory");

    const int rp = l >> 5;
    const int c4 = l & 31;
#pragma unroll
    for (int q = 0; q < 16; ++q) {
        f32x4 v = *(const f32x4*)&tz[w][q * 2 + rp][c4 * 4];
        *(f32x4*)(Out + (size_t)(rowbase + q * 2 + rp) * NN + colbase + c4 * 4) = v;
    }
}

// ---------------------------------------------------------------------------
extern "C" void kernel_launch(void* const* d_in, const int* in_sizes, int n_in,
                              void* d_out, int out_size, void* d_ws, size_t ws_size,
                              hipStream_t stream)
{
    // setup_inputs() order: H, A_buys, A_views, A_rates,
    //   W1_0, W2_0, W1_1, W2_1, W1_2, W2_2, b1, b2
    const float* H    = (const float*)d_in[0];
    const float* A0   = (const float*)d_in[1];
    const float* A1   = (const float*)d_in[2];
    const float* A2   = (const float*)d_in[3];
    const float* W1_0 = (const float*)d_in[4];
    const float* W2_0 = (const float*)d_in[5];
    const float* W1_1 = (const float*)d_in[6];
    const float* W2_1 = (const float*)d_in[7];
    const float* W1_2 = (const float*)d_in[8];
    const float* W2_2 = (const float*)d_in[9];
    const float* b1   = (const float*)d_in[10];
    const float* b2   = (const float*)d_in[11];

    float* Zout = (float*)d_out;                     // [8192][128]
    float* Ahat = (float*)d_out + (size_t)NN * EMBD; // [8192][8192], 256 MiB

    char* ws = (char*)d_ws;
    float*  P   = (float*)ws;                         // 32 MB partials (8 slabs)
    __bf16* Vp  = (__bf16*)(ws + ((size_t)32 << 20)); //  6 MB packed V (3 x 2MB)
    float*  H1  = (float*)(ws + ((size_t)38 << 20));  //  4 MB
    __bf16* Zb  = (__bf16*)(ws + ((size_t)42 << 20)); //  2 MB

    // Packed bf16 A: Apk0+Apk1 exactly fill the Ahat region (2 x 128 MiB);
    // zzt overwrites it last.  Apk2 goes to ws if there is room.
    __bf16* Apk0 = (__bf16*)Ahat;
    __bf16* Apk1 = Apk0 + (size_t)NN * NN;
    const bool full = ws_size >= ((size_t)184 << 20);
    __bf16* Apk2 = (__bf16*)(ws + ((size_t)48 << 20));

    // Layer 1 (f32 A; fused A->bf16 fragment compression)
    proj_pack<FEAT><<<256, 256, 0, stream>>>(H, W1_0, W1_1, W1_2, Vp);
    if (full) gemm_l1<true ><<<dim3(128, 8), 256, 0, stream>>>(A0, A1, A2, Vp, P, Apk0, Apk1, Apk2);
    else      gemm_l1<false><<<dim3(128, 8), 256, 0, stream>>>(A0, A1, A2, Vp, P, Apk0, Apk1, Apk2);
    reduce_relu<<<1024, 256, 0, stream>>>(P, b1, H1);

    // Layer 2 (packed bf16 A: half the read bytes)
    proj_pack<HIDD><<<256, 256, 0, stream>>>(H1, W2_0, W2_1, W2_2, Vp);
    if (full) gemm_l2<3><<<dim3(128, 8), 256, 0, stream>>>(A2, Apk0, Apk1, Apk2, Vp, P);
    else      gemm_l2<2><<<dim3(128, 8), 256, 0, stream>>>(A2, Apk0, Apk1, Apk2, Vp, P);
    reduce_z<<<1024, 256, 0, stream>>>(P, b2, Zout, Zb);

    // Decoder (overwrites Apk0/Apk1 scratch — must be last)
    zzt<<<dim3(64, 64), 256, 0, stream>>>(Zb, Ahat);
}

// Round 10
// 552.968 us; speedup vs baseline: 1.7395x; 1.0961x over previous
//
#include <hip/hip_runtime.h>
#include <hip/hip_bf16.h>

// Problem constants
#define NN    8192
#define FEAT  64
#define HIDD  128
#define EMBD  128

typedef __bf16 bf16x8 __attribute__((ext_vector_type(8)));
typedef float  f32x4  __attribute__((ext_vector_type(4)));

template<int AUX>
__device__ __forceinline__ void gload16(const void* g, void* l) {
    __builtin_amdgcn_global_load_lds(
        (const __attribute__((address_space(1))) void*)g,
        (__attribute__((address_space(3))) void*)l, 16, 0, AUX);
}

// ---------------------------------------------------------------------------
// proj_pack: V_r = X @ W_r^T into MFMA B-fragment layout (layer 1, X = H f32)
//   Vp elem ((r<<20) + kb*4096 + n*512 + l*8 + j) = V_r[kb*32+(l>>4)*8+j][n*16+(l&15)]
// ---------------------------------------------------------------------------
template<int KIN>
__global__ __launch_bounds__(256) void proj_pack(
    const float* __restrict__ X, const float* __restrict__ W0,
    const float* __restrict__ W1, const float* __restrict__ W2,
    __bf16* __restrict__ Vp)
{
    __shared__ float sx[32 * KIN];
    const int kb  = blockIdx.x;
    const int tid = threadIdx.x;
    {
        const f32x4* src = (const f32x4*)(X + (size_t)kb * 32 * KIN);
#pragma unroll
        for (int i = 0; i < 32 * KIN / 4 / 256; ++i)
            ((f32x4*)sx)[tid + i * 256] = src[tid + i * 256];
    }
    __syncthreads();

    const int c = tid & 127, h = tid >> 7;
    const int n = c >> 4, c15 = c & 15;
    const float* Ws[3] = {W0, W1, W2};
#pragma unroll
    for (int r = 0; r < 3; ++r) {
        f32x4 wreg[KIN / 4];
        const f32x4* wrow = (const f32x4*)(Ws[r] + (size_t)c * KIN);
#pragma unroll
        for (int j = 0; j < KIN / 4; ++j) wreg[j] = wrow[j];
        float d[16];
#pragma unroll
        for (int i = 0; i < 16; ++i) {
            const f32x4* xr = (const f32x4*)(sx + (h * 16 + i) * KIN);
            float s = 0.f;
#pragma unroll
            for (int j = 0; j < KIN / 4; ++j) {
                f32x4 xv = xr[j];
                s += xv[0]*wreg[j][0] + xv[1]*wreg[j][1] + xv[2]*wreg[j][2] + xv[3]*wreg[j][3];
            }
            d[i] = s;
        }
#pragma unroll
        for (int g = 0; g < 2; ++g) {
            bf16x8 b;
#pragma unroll
            for (int j = 0; j < 8; ++j) b[j] = (__bf16)d[g * 8 + j];
            const int l = (h * 2 + g) * 16 + c15;
            *(bf16x8*)(Vp + ((size_t)r << 20) + kb * 4096 + n * 512 + l * 8) = b;
        }
    }
}

// ---------------------------------------------------------------------------
// proj_hid: layer-2 projection FUSED with the layer-1 reduction.
// H1 rows kb*32..+31 are computed on the fly: relu(sum_p P[p] + b1), kept in
// LDS, then V2_r = H1 @ W2_r^T packed exactly like proj_pack. H1 never
// touches HBM, and the standalone reduce_relu kernel disappears.
// ---------------------------------------------------------------------------
__global__ __launch_bounds__(256) void proj_hid(
    const float* __restrict__ P, const float* __restrict__ b1,
    const float* __restrict__ W0, const float* __restrict__ W1,
    const float* __restrict__ W2, __bf16* __restrict__ Vp)
{
    __shared__ float sx[32 * HIDD];     // 16 KB
    const int kb  = blockIdx.x;
    const int tid = threadIdx.x;
    // accumulate 8 P slabs for this row-block (each thread owns 4 f32x4)
#pragma unroll
    for (int j = 0; j < 4; ++j) {
        const int idx = tid * 16 + j * 4;          // flat in [0,4096)
        f32x4 s = *(const f32x4*)(b1 + (idx & 127));
#pragma unroll
        for (int p = 0; p < 8; ++p)
            s += *(const f32x4*)(P + (size_t)p * (NN * 128) + (size_t)kb * 4096 + idx);
#pragma unroll
        for (int c = 0; c < 4; ++c) s[c] = s[c] > 0.f ? s[c] : 0.f;
        *(f32x4*)(sx + idx) = s;
    }
    __syncthreads();

    const int c = tid & 127, h = tid >> 7;
    const int n = c >> 4, c15 = c & 15;
    const float* Ws[3] = {W0, W1, W2};
#pragma unroll
    for (int r = 0; r < 3; ++r) {
        f32x4 wreg[HIDD / 4];
        const f32x4* wrow = (const f32x4*)(Ws[r] + (size_t)c * HIDD);
#pragma unroll
        for (int j = 0; j < HIDD / 4; ++j) wreg[j] = wrow[j];
        float d[16];
#pragma unroll
        for (int i = 0; i < 16; ++i) {
            const f32x4* xr = (const f32x4*)(sx + (h * 16 + i) * HIDD);
            float s = 0.f;
#pragma unroll
            for (int j = 0; j < HIDD / 4; ++j) {
                f32x4 xv = xr[j];
                s += xv[0]*wreg[j][0] + xv[1]*wreg[j][1] + xv[2]*wreg[j][2] + xv[3]*wreg[j][3];
            }
            d[i] = s;
        }
#pragma unroll
        for (int g = 0; g < 2; ++g) {
            bf16x8 b;
#pragma unroll
            for (int j = 0; j < 8; ++j) b[j] = (__bf16)d[g * 8 + j];
            const int l = (h * 2 + g) * 16 + c15;
            *(bf16x8*)(Vp + ((size_t)r << 20) + kb * 4096 + n * 512 + l * 8) = b;
        }
    }
}

// ---------------------------------------------------------------------------
// gemm_AV (R8 v8 structure, proven 218 us / 3.67 TB/s demand-side):
// BM=64 x BN=128, BK=32; 4 waves; 2x16KB LDS bufs; counted vmcnt(4); raw
// s_barrier; lgkmcnt guard; no vmcnt(0) in main loop. A staged with XOR
// 16B-block swizzle; A loads use NT cache policy (aux=2, zero-reuse stream);
// P stores nontemporal. Grid (128 mt, 8 ch) = 1024 blocks = 4/CU.
// ---------------------------------------------------------------------------
__global__ __launch_bounds__(256, 4) void gemm_AV(
    const float* __restrict__ A0, const float* __restrict__ A1,
    const float* __restrict__ A2,
    const __bf16* __restrict__ Vp, float* __restrict__ P)
{
    __shared__ __align__(16) unsigned char sbuf[2][16384];  // [A 8KB f32][B 8KB]

    const int mt = blockIdx.x, ch = blockIdx.y;
    const int tid = threadIdx.x;
    const int w = tid >> 6, l = tid & 63;
    const int l15 = l & 15, l4 = l >> 4;
    const int rowblk = mt * 64;

    f32x4 acc[8];
#pragma unroll
    for (int n = 0; n < 8; n++) acc[n] = (f32x4){0.f, 0.f, 0.f, 0.f};

    const int srow = l >> 3;                 // row-within-8-group == (row&7)
    const int sblk = (l & 7) ^ srow;         // inverse-swizzled source 16B block

    auto stage = [&](int t) {
        const int r = t >> 5, kk = t & 31;
        const float* Ar = (r == 0) ? A0 : (r == 1) ? A1 : A2;
        const int kglob = ch * 1024 + kk * 32;
        unsigned char* dst = sbuf[t & 1];
        const float* abase = Ar + (size_t)(rowblk + w * 16 + srow) * NN + kglob + sblk * 4;
#pragma unroll
        for (int j = 0; j < 2; ++j)
            gload16<2>(abase + (size_t)j * 8 * NN, dst + w * 2048 + j * 1024 + l * 16);
        const char* bsrc = (const char*)(Vp + ((size_t)r << 20)) + (size_t)(ch * 32 + kk) * 8192;
#pragma unroll
        for (int q = 0; q < 2; ++q)
            gload16<0>(bsrc + (w * 2 + q) * 1024 + l * 16,
                       dst + 8192 + (w * 2 + q) * 1024 + l * 16);
    };

    stage(0); stage(1);

    for (int t = 0; t < 96; ++t) {
        if (t < 95) asm volatile("s_waitcnt vmcnt(4)" ::: "memory");
        else        asm volatile("s_waitcnt vmcnt(0)" ::: "memory");
        __builtin_amdgcn_s_barrier();

        const unsigned char* buf = sbuf[t & 1];
        const int b0 = (2 * l4) ^ (l15 & 7);
        f32x4 lo = *(const f32x4*)(buf + w * 2048 + l15 * 128 + b0 * 16);
        f32x4 hi = *(const f32x4*)(buf + w * 2048 + l15 * 128 + (b0 ^ 1) * 16);
        bf16x8 af;
        af[0] = (__bf16)lo[0]; af[1] = (__bf16)lo[1];
        af[2] = (__bf16)lo[2]; af[3] = (__bf16)lo[3];
        af[4] = (__bf16)hi[0]; af[5] = (__bf16)hi[1];
        af[6] = (__bf16)hi[2]; af[7] = (__bf16)hi[3];
        bf16x8 bfr[8];
#pragma unroll
        for (int n = 0; n < 8; ++n)
            bfr[n] = *(const bf16x8*)(buf + 8192 + n * 1024 + l * 16);
#pragma unroll
        for (int n = 0; n < 8; ++n)
            acc[n] = __builtin_amdgcn_mfma_f32_16x16x32_bf16(af, bfr[n], acc[n], 0, 0, 0);

        asm volatile("s_waitcnt lgkmcnt(0)" ::: "memory");
        __builtin_amdgcn_s_barrier();
        if (t < 94) stage(t + 2);
    }

    // C/D layout: col = lane&15, row = (lane>>4)*4 + i ; NT scalar stores
    float* Pp = P + (size_t)ch * NN * 128;
#pragma unroll
    for (int n = 0; n < 8; n++) {
        int col = n * 16 + l15;
#pragma unroll
        for (int i = 0; i < 4; i++) {
            int row = rowblk + w * 16 + l4 * 4 + i;
            __builtin_nontemporal_store(acc[n][i], &Pp[(size_t)row * 128 + col]);
        }
    }
}

// ---------------------------------------------------------------------------
// reduce_z: sum 8 partial slabs + bias -> Zout (f32) and Zb (bf16)
// ---------------------------------------------------------------------------
__global__ __launch_bounds__(256) void reduce_z(
    const float* __restrict__ P, const float* __restrict__ bias,
    float* __restrict__ Zout, __bf16* __restrict__ Zb)
{
    size_t g = (size_t)blockIdx.x * 256 + threadIdx.x;
    size_t idx4 = g * 4;
    f32x4 s = *(const f32x4*)(bias + (idx4 & 127));
#pragma unroll
    for (int p = 0; p < 8; p++) s += *(const f32x4*)(P + (size_t)p * (NN * 128) + idx4);
    *(f32x4*)(Zout + idx4) = s;
#pragma unroll
    for (int c = 0; c < 4; c++) Zb[idx4 + c] = (__bf16)s[c];
}

// ---------------------------------------------------------------------------
// zzt: A_hat = Z @ Z^T with LDS-transposed, write-coalesced NT epilogue.
// ---------------------------------------------------------------------------
__global__ __launch_bounds__(256) void zzt(
    const __bf16* __restrict__ Zb, float* __restrict__ Out)
{
    __shared__ float tz[4][32][132];

    const int bx = blockIdx.x;
    const int by = blockIdx.y;
    const int tid = threadIdx.x;
    const int w = tid >> 6, l = tid & 63;
    const int l15 = l & 15, l4 = l >> 4;
    const int rowbase = by * 128 + w * 32;
    const int colbase = bx * 128;

    f32x4 acc[2][8];
#pragma unroll
    for (int m = 0; m < 2; m++)
#pragma unroll
        for (int n = 0; n < 8; n++) acc[m][n] = (f32x4){0.f, 0.f, 0.f, 0.f};

#pragma unroll
    for (int ks = 0; ks < 128; ks += 32) {
        bf16x8 af[2];
#pragma unroll
        for (int m = 0; m < 2; m++)
            af[m] = *(const bf16x8*)(Zb + (size_t)(rowbase + m * 16 + l15) * 128 + ks + l4 * 8);
#pragma unroll
        for (int n = 0; n < 8; n++) {
            bf16x8 bfr = *(const bf16x8*)(Zb + (size_t)(colbase + n * 16 + l15) * 128 + ks + l4 * 8);
            acc[0][n] = __builtin_amdgcn_mfma_f32_16x16x32_bf16(af[0], bfr, acc[0][n], 0, 0, 0);
            acc[1][n] = __builtin_amdgcn_mfma_f32_16x16x32_bf16(af[1], bfr, acc[1][n], 0, 0, 0);
        }
    }

#pragma unroll
    for (int m = 0; m < 2; m++)
#pragma unroll
        for (int n = 0; n < 8; n++)
#pragma unroll
            for (int i = 0; i < 4; i++)
                tz[w][m * 16 + l4 * 4 + i][n * 16 + l15] = acc[m][n][i];
    asm volatile("s_waitcnt lgkmcnt(0)" ::: "memory");

    const int rp = l >> 5;
    const int c4 = l & 31;
#pragma unroll
    for (int q = 0; q < 16; ++q) {
        f32x4 v = *(const f32x4*)&tz[w][q * 2 + rp][c4 * 4];
        __builtin_nontemporal_store(v,
            (f32x4*)(Out + (size_t)(rowbase + q * 2 + rp) * NN + colbase + c4 * 4));
    }
}

// ---------------------------------------------------------------------------
extern "C" void kernel_launch(void* const* d_in, const int* in_sizes, int n_in,
                              void* d_out, int out_size, void* d_ws, size_t ws_size,
                              hipStream_t stream)
{
    // setup_inputs() order: H, A_buys, A_views, A_rates,
    //   W1_0, W2_0, W1_1, W2_1, W1_2, W2_2, b1, b2
    const float* H    = (const float*)d_in[0];
    const float* A0   = (const float*)d_in[1];
    const float* A1   = (const float*)d_in[2];
    const float* A2   = (const float*)d_in[3];
    const float* W1_0 = (const float*)d_in[4];
    const float* W2_0 = (const float*)d_in[5];
    const float* W1_1 = (const float*)d_in[6];
    const float* W2_1 = (const float*)d_in[7];
    const float* W1_2 = (const float*)d_in[8];
    const float* W2_2 = (const float*)d_in[9];
    const float* b1   = (const float*)d_in[10];
    const float* b2   = (const float*)d_in[11];

    float* Zout = (float*)d_out;                     // [8192][128]
    float* Ahat = (float*)d_out + (size_t)NN * EMBD; // [8192][8192]

    char* ws = (char*)d_ws;
    float*  P   = (float*)ws;                         // 32 MB partials (8 slabs)
    __bf16* Vp  = (__bf16*)(ws + ((size_t)32 << 20)); //  6 MB packed V (3 x 2MB)
    __bf16* Zb  = (__bf16*)(ws + ((size_t)38 << 20)); //  2 MB

    // Layer 1
    proj_pack<FEAT><<<256, 256, 0, stream>>>(H, W1_0, W1_1, W1_2, Vp);
    gemm_AV<<<dim3(128, 8), 256, 0, stream>>>(A0, A1, A2, Vp, P);

    // Layer 2 (projection fused with layer-1 reduce+relu; H1 never hits HBM)
    proj_hid<<<256, 256, 0, stream>>>(P, b1, W2_0, W2_1, W2_2, Vp);
    gemm_AV<<<dim3(128, 8), 256, 0, stream>>>(A0, A1, A2, Vp, P);
    reduce_z<<<1024, 256, 0, stream>>>(P, b2, Zout, Zb);

    // Decoder
    zzt<<<dim3(64, 64), 256, 0, stream>>>(Zb, Ahat);
}